// Round 3
// baseline (383.149 us; speedup 1.0000x reference)
//
#include <hip/hip_runtime.h>

// ---------------------------------------------------------------------------
// BlockSparseAttention — de-fused fp16-MFMA pipeline, swizzled layouts (v3).
//  1) k_cvt_x : x fp32 -> xh fp16, swizzled row layout
//  2) k_cvt_w : Wq|Wk|Wv|Wo fp32 -> Wt[n][k] fp16 swizzled (one launch)
//  3) k_gemm_qkv: [16384x1024]x[1024x3072] GEMM; epilogue scatters Q,K
//     (row-major packed per (blk,head), bias+scale fused) and V^T.
//  4) k_attn : per (blk,head), 4 waves, zero LDS / zero barriers.
//  5) k_outproj: [16384x1024]x[1024x1024] GEMM, fp32 + bias out.
// Swizzle v3 (all fp16 operand matrices): within each row's 64B k-tile
// (32 k), k-group g (8 halves, k = 4g+16h+b at byte (4h+b)*2) is stored at
// 16B-slot (g + (row>>1)) & 3.  Fragment ds_read_b128: bank-span start =
// 16*(row&1) + 4*((g4+(row>>1))&3) -> each consecutive-8-lane oct covers all
// 32 banks exactly once -> conflict-free (fixes round-2's 2-way pattern:
// slot=(g+row)&3 made rows r and r+4 collide within an oct).
// Workspace (needs >= 136 MB): [0,32M) xh then ao | [32M,40M) Wt q,k,v,o |
// [40,72) Qp | [72,104) Kp | [104,136) Vp.
// ---------------------------------------------------------------------------

typedef _Float16 h16;
typedef _Float16 half8 __attribute__((ext_vector_type(8)));
typedef _Float16 half4 __attribute__((ext_vector_type(4)));
typedef float    f32x4 __attribute__((ext_vector_type(4)));
typedef float    fvec4 __attribute__((ext_vector_type(4)));

__device__ __forceinline__ void gload16(const void* g, void* l) {
  __builtin_amdgcn_global_load_lds(
      (const __attribute__((address_space(1))) unsigned int*)g,
      (__attribute__((address_space(3))) unsigned int*)l, 16, 0, 0);
}
#define MFMA16(a, b, c) __builtin_amdgcn_mfma_f32_16x16x32_f16(a, b, c, 0, 0, 0)

// ---------------- kernel 1: x fp32 -> fp16, swizzled -----------------------
__global__ __launch_bounds__(256) void k_cvt_x(const float* __restrict__ x,
                                               h16* __restrict__ xh) {
  size_t t = (size_t)blockIdx.x * 256 + threadIdx.x;  // (token, ktile) pairs
  int token = (int)(t >> 5);
  const fvec4* src = (const fvec4*)(x + t * 32);
  fvec4 f[8];
#pragma unroll
  for (int m = 0; m < 8; ++m) f[m] = src[m];
  h16* dst = xh + t * 32;  // = token*1024 + kt*32 halves
#pragma unroll
  for (int t4 = 0; t4 < 4; ++t4) {
    int g = (t4 - (token >> 1)) & 3;      // slot t4 holds group g
    half8 o;
#pragma unroll
    for (int j = 0; j < 8; ++j) o[j] = (h16)f[g + 4 * (j >> 2)][j & 3];
    *(half8*)(dst + t4 * 8) = o;
  }
}

// ------- kernel 2: W[k][n] fp32 -> Wt[n][k] fp16 swizzled, 4 mats ----------
__global__ __launch_bounds__(256) void k_cvt_w(
    const float* __restrict__ W0, const float* __restrict__ W1,
    const float* __restrict__ W2, const float* __restrict__ W3,
    h16* __restrict__ Wt_all) {
  __shared__ float T[64][33];
  int bid = blockIdx.x;                 // 2048 = 4 mats x 512
  int mat = bid >> 9, b2 = bid & 511;
  const float* W = (mat == 0) ? W0 : (mat == 1) ? W1 : (mat == 2) ? W2 : W3;
  h16* Wt = Wt_all + (size_t)mat * 1024 * 1024;
  int n0 = (b2 & 31) * 32;
  int k0 = (b2 >> 5) * 64;
  int tid = threadIdx.x;
#pragma unroll
  for (int it = 0; it < 2; ++it) {
    int s = it * 256 + tid;
    int r = s >> 3, c4 = s & 7;
    fvec4 v = *(const fvec4*)(W + (size_t)(k0 + r) * 1024 + n0 + c4 * 4);
#pragma unroll
    for (int j = 0; j < 4; ++j) T[r][c4 * 4 + j] = v[j];
  }
  __syncthreads();
  int n = tid >> 3, j = tid & 7;
  int kb = j >> 2, g = j & 3;
  half8 o;
#pragma unroll
  for (int h = 0; h < 2; ++h)
#pragma unroll
    for (int b = 0; b < 4; ++b)
      o[h * 4 + b] = (h16)T[kb * 32 + 4 * g + 16 * h + b][n];
  int nn = n0 + n;
  int slot = (g + (nn >> 1)) & 3;
  *(half8*)(Wt + (size_t)nn * 1024 + ((k0 >> 5) + kb) * 32 + slot * 8) = o;
}

// --------- kernel 3: QKV GEMM 16384x3072, epilogue packs Q/K/V^T -----------
__global__ __launch_bounds__(256) void k_gemm_qkv(
    const h16* __restrict__ xh, const h16* __restrict__ wt,
    const float* __restrict__ bq, const float* __restrict__ bk,
    const float* __restrict__ bv, h16* __restrict__ Qp,
    h16* __restrict__ Kp, h16* __restrict__ Vp) {
  __shared__ h16 A[128 * 32];
  __shared__ h16 B[128 * 32];
  int bid = blockIdx.x;                      // 3072 = 8 XCD x 384
  int t = (bid & 7) * 384 + (bid >> 3);
  int mt = t / 24, nt = t - mt * 24;
  int tid = threadIdx.x, w = tid >> 6, lane = tid & 63;
  int l15 = lane & 15, g4 = lane >> 4;
  int slotr = ((g4 + (l15 >> 1)) & 3) * 8;   // conflict-free frag slot
  int wr = w >> 1, wc = w & 1;
  size_t m0 = (size_t)mt * 128;
  f32x4 acc[4][4] = {};
  for (int kt = 0; kt < 32; ++kt) {
#pragma unroll
    for (int j = 0; j < 2; ++j) {
      int s = j * 256 + tid;
      int r = s >> 2, t4 = s & 3;
      gload16(xh + (m0 + r) * 1024 + kt * 32 + t4 * 8, &A[(j * 256 + w * 64) * 8]);
      gload16(wt + (size_t)(nt * 128 + r) * 1024 + kt * 32 + t4 * 8,
              &B[(j * 256 + w * 64) * 8]);
    }
    __syncthreads();
    half8 a[4], b[4];
#pragma unroll
    for (int mi = 0; mi < 4; ++mi)
      a[mi] = *(const half8*)&A[(wr * 64 + mi * 16 + l15) * 32 + slotr];
#pragma unroll
    for (int nj = 0; nj < 4; ++nj)
      b[nj] = *(const half8*)&B[(wc * 64 + nj * 16 + l15) * 32 + slotr];
#pragma unroll
    for (int nj = 0; nj < 4; ++nj)
#pragma unroll
      for (int mi = 0; mi < 4; ++mi) acc[mi][nj] = MFMA16(a[mi], b[nj], acc[mi][nj]);
    __syncthreads();
  }
  // epilogue: scatter to packed per-(blk,head) buffers
  int mat = nt >> 3;                 // 0=Q 1=K 2=V
  int hbase = (nt & 7) * 2;
  int blk = mt;
  const float sc = 0.125f * 1.44269504088896f;  // 1/sqrt(dk)*log2(e)
#pragma unroll
  for (int mi = 0; mi < 4; ++mi)
#pragma unroll
    for (int nj = 0; nj < 4; ++nj) {
      int c = wc * 64 + nj * 16 + l15;
      int head = hbase + (c >> 6), d = c & 63;
      int tok0 = wr * 64 + mi * 16 + g4 * 4;
      size_t bh8k = (size_t)(blk * 16 + head) * 8192;
      if (mat == 0) {
        float bias = bq[head * 64 + d];
        int inner = ((d >> 4) & 1) * 4 + (d & 3), gq = (d & 15) >> 2, dk5 = d >> 5;
#pragma unroll
        for (int r = 0; r < 4; ++r) {
          int tok = tok0 + r;
          Qp[bh8k + tok * 64 + dk5 * 32 + ((gq + (tok >> 1)) & 3) * 8 + inner] =
              (h16)((acc[mi][nj][r] + bias) * sc);
        }
      } else if (mat == 1) {
        float bias = bk[head * 64 + d];
        int inner = ((d >> 4) & 1) * 4 + (d & 3), gq = (d & 15) >> 2, dk5 = d >> 5;
#pragma unroll
        for (int r = 0; r < 4; ++r) {
          int tok = tok0 + r;
          Kp[bh8k + tok * 64 + dk5 * 32 + ((gq + (tok >> 1)) & 3) * 8 + inner] =
              (h16)(acc[mi][nj][r] + bias);
        }
      } else {
        float bias = bv[head * 64 + d];
        half4 v4;
#pragma unroll
        for (int r = 0; r < 4; ++r) v4[r] = (h16)(acc[mi][nj][r] + bias);
        *(half4*)&Vp[bh8k + d * 128 + (tok0 >> 5) * 32 +
                     ((g4 + (d >> 1)) & 3) * 8 + (mi & 1) * 4] = v4;
      }
    }
}

// --------- kernel 4: block attention, zero LDS / zero barriers -------------
__global__ __launch_bounds__(256) void k_attn(
    const h16* __restrict__ Qp, const h16* __restrict__ Kp,
    const h16* __restrict__ Vp, h16* __restrict__ ao) {
  int bh = blockIdx.x;                       // 2048 = 128 blk x 16 heads
  int blk = bh >> 4, head = bh & 15;
  int tid = threadIdx.x, w = tid >> 6, lane = tid & 63;
  int l15 = lane & 15, g4 = lane >> 4;
  const h16* Qb = Qp + (size_t)bh * 8192;
  const h16* Kb = Kp + (size_t)bh * 8192;
  const h16* Vb = Vp + (size_t)bh * 8192;

  half8 qb[2][2];
#pragma unroll
  for (int cf = 0; cf < 2; ++cf)
#pragma unroll
    for (int k2 = 0; k2 < 2; ++k2) {
      int q = w * 32 + cf * 16 + l15;
      qb[cf][k2] = *(const half8*)(Qb + q * 64 + k2 * 32 + ((g4 + (q >> 1)) & 3) * 8);
    }
  f32x4 sacc[8][2] = {};
#pragma unroll
  for (int k2 = 0; k2 < 2; ++k2)
#pragma unroll
    for (int Rf = 0; Rf < 8; ++Rf) {
      int kv = Rf * 16 + l15;
      half8 ka = *(const half8*)(Kb + kv * 64 + k2 * 32 + ((g4 + (kv >> 1)) & 3) * 8);
      sacc[Rf][0] = MFMA16(ka, qb[0][k2], sacc[Rf][0]);
      sacc[Rf][1] = MFMA16(ka, qb[1][k2], sacc[Rf][1]);
    }
  // softmax over kv (S^T rows): lane-local 32 + xor 16,32
  float rmax[2] = {-1e30f, -1e30f};
#pragma unroll
  for (int Rf = 0; Rf < 8; ++Rf)
#pragma unroll
    for (int cf = 0; cf < 2; ++cf)
#pragma unroll
      for (int r = 0; r < 4; ++r) rmax[cf] = fmaxf(rmax[cf], sacc[Rf][cf][r]);
#pragma unroll
  for (int cf = 0; cf < 2; ++cf) {
    rmax[cf] = fmaxf(rmax[cf], __shfl_xor(rmax[cf], 16, 64));
    rmax[cf] = fmaxf(rmax[cf], __shfl_xor(rmax[cf], 32, 64));
  }
  float rsum[2] = {0.f, 0.f};
#pragma unroll
  for (int Rf = 0; Rf < 8; ++Rf)
#pragma unroll
    for (int cf = 0; cf < 2; ++cf)
#pragma unroll
      for (int r = 0; r < 4; ++r) {
        float p = exp2f(sacc[Rf][cf][r] - rmax[cf]);
        sacc[Rf][cf][r] = p;
        rsum[cf] += p;
      }
#pragma unroll
  for (int cf = 0; cf < 2; ++cf) {
    rsum[cf] += __shfl_xor(rsum[cf], 16, 64);
    rsum[cf] += __shfl_xor(rsum[cf], 32, 64);
    rsum[cf] = 1.0f / rsum[cf];
  }
  // O^T = V^T * P^T  (S^T C-frags feed P^T B-frags directly)
  f32x4 oacc[4][2] = {};
#pragma unroll
  for (int kb = 0; kb < 4; ++kb) {
    half8 pb[2];
#pragma unroll
    for (int cf = 0; cf < 2; ++cf) {
      half8 tt;
#pragma unroll
      for (int hb = 0; hb < 8; ++hb)
        tt[hb] = (h16)sacc[2 * kb + (hb >> 2)][cf][hb & 3];
      pb[cf] = tt;
    }
#pragma unroll
    for (int dR = 0; dR < 4; ++dR) {
      int dd = dR * 16 + l15;
      half8 va = *(const half8*)(Vb + dd * 128 + kb * 32 +
                                 ((g4 + (dd >> 1)) & 3) * 8);
      oacc[dR][0] = MFMA16(va, pb[0], oacc[dR][0]);
      oacc[dR][1] = MFMA16(va, pb[1], oacc[dR][1]);
    }
  }
  // store ao (swizzled A-layout for outproj), half4 per frag
#pragma unroll
  for (int dR = 0; dR < 4; ++dR)
#pragma unroll
    for (int cf = 0; cf < 2; ++cf) {
      int tok127 = w * 32 + cf * 16 + l15;
      size_t token = (size_t)blk * 128 + tok127;
      half4 v4;
#pragma unroll
      for (int r = 0; r < 4; ++r) v4[r] = (h16)(oacc[dR][cf][r] * rsum[cf]);
      *(half4*)&ao[token * 1024 + (2 * head + (dR >> 1)) * 32 +
                   ((g4 + (tok127 >> 1)) & 3) * 8 + (dR & 1) * 4] = v4;
    }
}

// ----------------- kernel 5: out = ao * Wo^T + bo (fp32) -------------------
__global__ __launch_bounds__(256) void k_outproj(
    const h16* __restrict__ ao, const h16* __restrict__ Wto,
    const float* __restrict__ bo, float* __restrict__ out) {
  __shared__ h16 A[128 * 32];
  __shared__ h16 B[128 * 32];
  int bid = blockIdx.x;                      // 1024
  int tile = (bid & 7) * 128 + (bid >> 3);
  int mt = tile >> 3, nt = tile & 7;
  size_t m0 = (size_t)mt * 128;
  int n0 = nt * 128;
  int tid = threadIdx.x, w = tid >> 6, lane = tid & 63;
  int l15 = lane & 15, g4 = lane >> 4;
  int slotr = ((g4 + (l15 >> 1)) & 3) * 8;
  int wr = w >> 1, wc = w & 1;
  f32x4 acc[4][4] = {};
  for (int kt = 0; kt < 32; ++kt) {
#pragma unroll
    for (int j = 0; j < 2; ++j) {
      int s = j * 256 + tid;
      int r = s >> 2, t4 = s & 3;
      gload16(ao + (m0 + r) * 1024 + kt * 32 + t4 * 8, &A[(j * 256 + w * 64) * 8]);
      gload16(Wto + (size_t)(n0 + r) * 1024 + kt * 32 + t4 * 8,
              &B[(j * 256 + w * 64) * 8]);
    }
    __syncthreads();
    half8 a[4], b[4];
#pragma unroll
    for (int mi = 0; mi < 4; ++mi)
      a[mi] = *(const half8*)&A[(wr * 64 + mi * 16 + l15) * 32 + slotr];
#pragma unroll
    for (int nj = 0; nj < 4; ++nj)
      b[nj] = *(const half8*)&B[(wc * 64 + nj * 16 + l15) * 32 + slotr];
#pragma unroll
    for (int nj = 0; nj < 4; ++nj)
#pragma unroll
      for (int mi = 0; mi < 4; ++mi) acc[mi][nj] = MFMA16(a[mi], b[nj], acc[mi][nj]);
    __syncthreads();
  }
#pragma unroll
  for (int mi = 0; mi < 4; ++mi)
#pragma unroll
    for (int nj = 0; nj < 4; ++nj) {
      int col = n0 + wc * 64 + nj * 16 + l15;
      float bb = bo[col];
      size_t rowb = m0 + wr * 64 + mi * 16 + 4 * g4;
#pragma unroll
      for (int r = 0; r < 4; ++r)
        out[(rowb + r) * 1024 + col] = acc[mi][nj][r] + bb;
    }
}

// ---------------------------------------------------------------------------
extern "C" void kernel_launch(void* const* d_in, const int* in_sizes, int n_in,
                              void* d_out, int out_size, void* d_ws, size_t ws_size,
                              hipStream_t stream) {
  const float* x  = (const float*)d_in[0];
  const float* Wq = (const float*)d_in[1];
  const float* bq = (const float*)d_in[2];
  const float* Wk = (const float*)d_in[3];
  const float* bk = (const float*)d_in[4];
  const float* Wv = (const float*)d_in[5];
  const float* bv = (const float*)d_in[6];
  const float* Wo = (const float*)d_in[7];
  const float* bo = (const float*)d_in[8];
  float* out = (float*)d_out;

  char* ws = (char*)d_ws;                  // needs >= 136 MB
  h16* xh = (h16*)ws;                      // 32 MB (reused as ao after QKV GEMM)
  h16* wt = (h16*)(ws + (32u << 20));      // 8 MB: q,k,v,o consecutive
  h16* Qp = (h16*)(ws + (40u << 20));      // 32 MB
  h16* Kp = (h16*)(ws + (72u << 20));      // 32 MB
  h16* Vp = (h16*)(ws + (104u << 20));     // 32 MB
  h16* ao = xh;                            // alias: xh dead after k_gemm_qkv

  k_cvt_x<<<2048, 256, 0, stream>>>(x, xh);
  k_cvt_w<<<2048, 256, 0, stream>>>(Wq, Wk, Wv, Wo, wt);
  k_gemm_qkv<<<3072, 256, 0, stream>>>(xh, wt, bq, bk, bv, Qp, Kp, Vp);
  k_attn<<<2048, 256, 0, stream>>>(Qp, Kp, Vp, ao);
  k_outproj<<<1024, 256, 0, stream>>>(ao, wt + 3u * 1024 * 1024, bo, out);
}

// Round 5
// 350.943 us; speedup vs baseline: 1.0918x; 1.0918x over previous
//
#include <hip/hip_runtime.h>

// ---------------------------------------------------------------------------
// BlockSparseAttention — fp16-MFMA pipeline, 256^2 8-phase GEMMs (v4).
//  1) k_cvt_x : x fp32 -> xh fp16, swizzled row layout          (unchanged)
//  2) k_cvt_w : W* fp32 -> Wt[n][k] fp16 swizzled, 4 mats       (unchanged)
//  3) k_gemm_qkv: [16384x1024]x[1024x3072], 256^2 tile, BK=64, 8 waves,
//     4-phase/K-tile pipelined (counted vmcnt(4), setprio, dbuf LDS);
//     epilogue scatters Q,K (bias+scale fused) and V^T per (blk,head).
//  4) k_attn : per (blk,head), 4 waves, zero LDS / zero barriers (unchanged)
//  5) k_outproj: [16384x1024]x[1024x1024], same 256^2 core, fp32+bias out.
// Swizzle (all fp16 operand matrices): within each row's 64B k-tile (32 k),
// k-group g (8 halves, k=4g+16h+b at byte (4h+b)*2) stored at 16B-slot
// (g + (row>>1)) & 3.  LDS inherits it (linear gload_lds copy of 64B units);
// frag ds_read_b128 slot (g4+(l15>>1))&3 -> conflict-free (r3-verified: 0).
// Workspace (needs >= 136 MB): [0,32M) xh then ao | [32M,40M) Wt q,k,v,o |
// [40,72) Qp | [72,104) Kp | [104,136) Vp.
// ---------------------------------------------------------------------------

typedef _Float16 h16;
typedef _Float16 half8 __attribute__((ext_vector_type(8)));
typedef _Float16 half4 __attribute__((ext_vector_type(4)));
typedef float    f32x4 __attribute__((ext_vector_type(4)));
typedef float    fvec4 __attribute__((ext_vector_type(4)));

__device__ __forceinline__ void gload16(const void* g, void* l) {
  __builtin_amdgcn_global_load_lds(
      (const __attribute__((address_space(1))) unsigned int*)g,
      (__attribute__((address_space(3))) unsigned int*)l, 16, 0, 0);
}
#define MFMA16(a, b, c) __builtin_amdgcn_mfma_f32_16x16x32_f16(a, b, c, 0, 0, 0)

// ---------------- kernel 1: x fp32 -> fp16, swizzled -----------------------
__global__ __launch_bounds__(256) void k_cvt_x(const float* __restrict__ x,
                                               h16* __restrict__ xh) {
  size_t t = (size_t)blockIdx.x * 256 + threadIdx.x;
  int token = (int)(t >> 5);
  const fvec4* src = (const fvec4*)(x + t * 32);
  fvec4 f[8];
#pragma unroll
  for (int m = 0; m < 8; ++m) f[m] = src[m];
  h16* dst = xh + t * 32;
#pragma unroll
  for (int t4 = 0; t4 < 4; ++t4) {
    int g = (t4 - (token >> 1)) & 3;
    half8 o;
#pragma unroll
    for (int j = 0; j < 8; ++j) o[j] = (h16)f[g + 4 * (j >> 2)][j & 3];
    *(half8*)(dst + t4 * 8) = o;
  }
}

// ------- kernel 2: W[k][n] fp32 -> Wt[n][k] fp16 swizzled, 4 mats ----------
__global__ __launch_bounds__(256) void k_cvt_w(
    const float* __restrict__ W0, const float* __restrict__ W1,
    const float* __restrict__ W2, const float* __restrict__ W3,
    h16* __restrict__ Wt_all) {
  __shared__ float T[64][33];
  int bid = blockIdx.x;
  int mat = bid >> 9, b2 = bid & 511;
  const float* W = (mat == 0) ? W0 : (mat == 1) ? W1 : (mat == 2) ? W2 : W3;
  h16* Wt = Wt_all + (size_t)mat * 1024 * 1024;
  int n0 = (b2 & 31) * 32;
  int k0 = (b2 >> 5) * 64;
  int tid = threadIdx.x;
#pragma unroll
  for (int it = 0; it < 2; ++it) {
    int s = it * 256 + tid;
    int r = s >> 3, c4 = s & 7;
    fvec4 v = *(const fvec4*)(W + (size_t)(k0 + r) * 1024 + n0 + c4 * 4);
#pragma unroll
    for (int j = 0; j < 4; ++j) T[r][c4 * 4 + j] = v[j];
  }
  __syncthreads();
  int n = tid >> 3, j = tid & 7;
  int kb = j >> 2, g = j & 3;
  half8 o;
#pragma unroll
  for (int h = 0; h < 2; ++h)
#pragma unroll
    for (int b = 0; b < 4; ++b)
      o[h * 4 + b] = (h16)T[kb * 32 + 4 * g + 16 * h + b][n];
  int nn = n0 + n;
  int slot = (g + (nn >> 1)) & 3;
  *(half8*)(Wt + (size_t)nn * 1024 + ((k0 >> 5) + kb) * 32 + slot * 8) = o;
}

// ----------------- 256^2 / BK=64 pipelined GEMM core -----------------------
// A[M,1024], B[N,1024] both row-major swizzled fp16. 512 thr = 8 waves
// (wr=w>>2 in {0,1}: 128 A-rows; wc=w&3: 64 B-rows). acc[fi][fj] holds
// C(row = wr*128+fi*16+4*g4+rr, col = wc*64+fj*16+l15).
__device__ __forceinline__ void gemm256(const h16* __restrict__ Ag,
                                        const h16* __restrict__ Bg,
                                        int tid, f32x4 (&acc)[8][4]) {
  __shared__ h16 LA[4][8192];  // [buf*2+kk][256 rows * 32 halves]
  __shared__ h16 LB[4][8192];
  const int w = tid >> 6, lane = tid & 63, l15 = lane & 15, g4 = lane >> 4;
  const int wr = w >> 2, wc = w & 3;
  const int slotr = ((g4 + (l15 >> 1)) & 3) * 8;
  const int arow0 = (wr * 128 + l15) * 32 + slotr;  // + fi*512
  const int brow0 = (wc * 64 + l15) * 32 + slotr;   // + fj*512

  auto stage = [&](const h16* g0, h16* ldsu) {      // one 16KB unit, 2 gloads
#pragma unroll
    for (int j = 0; j < 2; ++j) {
      int idx = j * 512 + tid;
      gload16(g0 + (size_t)(idx >> 2) * 1024 + (idx & 3) * 8,
              ldsu + (j * 512 + w * 64) * 8);
    }
  };

  // prologue: tile 0 (units: A-kk0, B-kk0, A-kk1, B-kk1)
  stage(Ag + 0 * 32, LA[0]);
  stage(Bg + 0 * 32, LB[0]);
  stage(Ag + 1 * 32, LA[1]);
  stage(Bg + 1 * 32, LB[1]);
  asm volatile("s_waitcnt vmcnt(4)" ::: "memory");  // kk0 units landed
  __builtin_amdgcn_s_barrier();

  half8 a[8], b[4];
  for (int t = 0; t < 16; ++t) {
    const int cb = (t & 1) * 2, nb = cb ^ 2;
    const bool pre = (t + 1) < 16;
    // ---- P0: kk0, fj 0-1 ----
#pragma unroll
    for (int fi = 0; fi < 8; ++fi)
      a[fi] = *(const half8*)&LA[cb][arow0 + fi * 512];
    b[0] = *(const half8*)&LB[cb][brow0 + 0 * 512];
    b[1] = *(const half8*)&LB[cb][brow0 + 1 * 512];
    if (pre) stage(Ag + (size_t)(2 * (t + 1)) * 32, LA[nb]);
    __builtin_amdgcn_s_barrier();
    asm volatile("s_waitcnt lgkmcnt(0)" ::: "memory");
    __builtin_amdgcn_sched_barrier(0);
    __builtin_amdgcn_s_setprio(1);
#pragma unroll
    for (int fi = 0; fi < 8; ++fi) {
      acc[fi][0] = MFMA16(a[fi], b[0], acc[fi][0]);
      acc[fi][1] = MFMA16(a[fi], b[1], acc[fi][1]);
    }
    __builtin_amdgcn_s_setprio(0);
    __builtin_amdgcn_s_barrier();
    // ---- P1: kk0, fj 2-3 ----
    b[2] = *(const half8*)&LB[cb][brow0 + 2 * 512];
    b[3] = *(const half8*)&LB[cb][brow0 + 3 * 512];
    if (pre) stage(Bg + (size_t)(2 * (t + 1)) * 32, LB[nb]);
    if (pre) asm volatile("s_waitcnt vmcnt(4)" ::: "memory");  // t's kk1 done
    else     asm volatile("s_waitcnt vmcnt(0)" ::: "memory");
    __builtin_amdgcn_s_barrier();
    asm volatile("s_waitcnt lgkmcnt(0)" ::: "memory");
    __builtin_amdgcn_sched_barrier(0);
    __builtin_amdgcn_s_setprio(1);
#pragma unroll
    for (int fi = 0; fi < 8; ++fi) {
      acc[fi][2] = MFMA16(a[fi], b[2], acc[fi][2]);
      acc[fi][3] = MFMA16(a[fi], b[3], acc[fi][3]);
    }
    __builtin_amdgcn_s_setprio(0);
    __builtin_amdgcn_s_barrier();
    // ---- P2: kk1, fj 0-1 ----
#pragma unroll
    for (int fi = 0; fi < 8; ++fi)
      a[fi] = *(const half8*)&LA[cb + 1][arow0 + fi * 512];
    b[0] = *(const half8*)&LB[cb + 1][brow0 + 0 * 512];
    b[1] = *(const half8*)&LB[cb + 1][brow0 + 1 * 512];
    if (pre) stage(Ag + (size_t)(2 * (t + 1) + 1) * 32, LA[nb + 1]);
    __builtin_amdgcn_s_barrier();
    asm volatile("s_waitcnt lgkmcnt(0)" ::: "memory");
    __builtin_amdgcn_sched_barrier(0);
    __builtin_amdgcn_s_setprio(1);
#pragma unroll
    for (int fi = 0; fi < 8; ++fi) {
      acc[fi][0] = MFMA16(a[fi], b[0], acc[fi][0]);
      acc[fi][1] = MFMA16(a[fi], b[1], acc[fi][1]);
    }
    __builtin_amdgcn_s_setprio(0);
    __builtin_amdgcn_s_barrier();
    // ---- P3: kk1, fj 2-3 ----
    b[2] = *(const half8*)&LB[cb + 1][brow0 + 2 * 512];
    b[3] = *(const half8*)&LB[cb + 1][brow0 + 3 * 512];
    if (pre) stage(Bg + (size_t)(2 * (t + 1) + 1) * 32, LB[nb + 1]);
    if (pre) asm volatile("s_waitcnt vmcnt(4)" ::: "memory");  // t+1 kk0 done
    __builtin_amdgcn_s_barrier();
    asm volatile("s_waitcnt lgkmcnt(0)" ::: "memory");
    __builtin_amdgcn_sched_barrier(0);
    __builtin_amdgcn_s_setprio(1);
#pragma unroll
    for (int fi = 0; fi < 8; ++fi) {
      acc[fi][2] = MFMA16(a[fi], b[2], acc[fi][2]);
      acc[fi][3] = MFMA16(a[fi], b[3], acc[fi][3]);
    }
    __builtin_amdgcn_s_setprio(0);
    __builtin_amdgcn_s_barrier();
  }
}

// --------- kernel 3: QKV GEMM 16384x3072, epilogue packs Q/K/V^T -----------
__global__ __launch_bounds__(512, 2) void k_gemm_qkv(
    const h16* __restrict__ xh, const h16* __restrict__ wt,
    const float* __restrict__ bq, const float* __restrict__ bk,
    const float* __restrict__ bv, h16* __restrict__ Qp,
    h16* __restrict__ Kp, h16* __restrict__ Vp) {
  int bid = blockIdx.x;                       // 768 = 8 XCD x 96
  int wg = (bid & 7) * 96 + (bid >> 3);
  int mt = wg / 12, nt = wg - mt * 12;
  int tid = threadIdx.x;
  f32x4 acc[8][4] = {};
  gemm256(xh + (size_t)mt * 256 * 1024, wt + (size_t)nt * 256 * 1024, tid, acc);

  const int w = tid >> 6, lane = tid & 63, l15 = lane & 15, g4 = lane >> 4;
  const int wr = w >> 2, wc = w & 3;
  int mat = nt >> 2;                          // 0=Q 1=K 2=V
  int head = (nt & 3) * 4 + wc;               // wave-uniform
  int blk = mt * 2 + wr;
  size_t bh8k = (size_t)(blk * 16 + head) * 8192;
  const float sc = 0.125f * 1.44269504088896f;  // 1/sqrt(dk)*log2(e)
#pragma unroll
  for (int fi = 0; fi < 8; ++fi)
#pragma unroll
    for (int fj = 0; fj < 4; ++fj) {
      int d = fj * 16 + l15;
      int tok0 = fi * 16 + 4 * g4;
      if (mat == 0) {
        float bias = bq[head * 64 + d];
        int inner = ((d >> 4) & 1) * 4 + (d & 3), gq = (d & 15) >> 2, dk5 = d >> 5;
#pragma unroll
        for (int rr = 0; rr < 4; ++rr) {
          int tok = tok0 + rr;
          Qp[bh8k + tok * 64 + dk5 * 32 + ((gq + (tok >> 1)) & 3) * 8 + inner] =
              (h16)((acc[fi][fj][rr] + bias) * sc);
        }
      } else if (mat == 1) {
        float bias = bk[head * 64 + d];
        int inner = ((d >> 4) & 1) * 4 + (d & 3), gq = (d & 15) >> 2, dk5 = d >> 5;
#pragma unroll
        for (int rr = 0; rr < 4; ++rr) {
          int tok = tok0 + rr;
          Kp[bh8k + tok * 64 + dk5 * 32 + ((gq + (tok >> 1)) & 3) * 8 + inner] =
              (h16)(acc[fi][fj][rr] + bias);
        }
      } else {
        float bias = bv[head * 64 + d];
        half4 v4;
#pragma unroll
        for (int rr = 0; rr < 4; ++rr) v4[rr] = (h16)(acc[fi][fj][rr] + bias);
        *(half4*)&Vp[bh8k + d * 128 + (fi >> 1) * 32 +
                     ((g4 + (d >> 1)) & 3) * 8 + (fi & 1) * 4] = v4;
      }
    }
}

// --------- kernel 4: block attention, zero LDS / zero barriers -------------
__global__ __launch_bounds__(256) void k_attn(
    const h16* __restrict__ Qp, const h16* __restrict__ Kp,
    const h16* __restrict__ Vp, h16* __restrict__ ao) {
  int bh = blockIdx.x;                       // 2048 = 128 blk x 16 heads
  int blk = bh >> 4, head = bh & 15;
  int tid = threadIdx.x, w = tid >> 6, lane = tid & 63;
  int l15 = lane & 15, g4 = lane >> 4;
  const h16* Qb = Qp + (size_t)bh * 8192;
  const h16* Kb = Kp + (size_t)bh * 8192;
  const h16* Vb = Vp + (size_t)bh * 8192;

  half8 qb[2][2];
#pragma unroll
  for (int cf = 0; cf < 2; ++cf)
#pragma unroll
    for (int k2 = 0; k2 < 2; ++k2) {
      int q = w * 32 + cf * 16 + l15;
      qb[cf][k2] = *(const half8*)(Qb + q * 64 + k2 * 32 + ((g4 + (q >> 1)) & 3) * 8);
    }
  f32x4 sacc[8][2] = {};
#pragma unroll
  for (int k2 = 0; k2 < 2; ++k2)
#pragma unroll
    for (int Rf = 0; Rf < 8; ++Rf) {
      int kv = Rf * 16 + l15;
      half8 ka = *(const half8*)(Kb + kv * 64 + k2 * 32 + ((g4 + (kv >> 1)) & 3) * 8);
      sacc[Rf][0] = MFMA16(ka, qb[0][k2], sacc[Rf][0]);
      sacc[Rf][1] = MFMA16(ka, qb[1][k2], sacc[Rf][1]);
    }
  float rmax[2] = {-1e30f, -1e30f};
#pragma unroll
  for (int Rf = 0; Rf < 8; ++Rf)
#pragma unroll
    for (int cf = 0; cf < 2; ++cf)
#pragma unroll
      for (int r = 0; r < 4; ++r) rmax[cf] = fmaxf(rmax[cf], sacc[Rf][cf][r]);
#pragma unroll
  for (int cf = 0; cf < 2; ++cf) {
    rmax[cf] = fmaxf(rmax[cf], __shfl_xor(rmax[cf], 16, 64));
    rmax[cf] = fmaxf(rmax[cf], __shfl_xor(rmax[cf], 32, 64));
  }
  float rsum[2] = {0.f, 0.f};
#pragma unroll
  for (int Rf = 0; Rf < 8; ++Rf)
#pragma unroll
    for (int cf = 0; cf < 2; ++cf)
#pragma unroll
      for (int r = 0; r < 4; ++r) {
        float p = exp2f(sacc[Rf][cf][r] - rmax[cf]);
        sacc[Rf][cf][r] = p;
        rsum[cf] += p;
      }
#pragma unroll
  for (int cf = 0; cf < 2; ++cf) {
    rsum[cf] += __shfl_xor(rsum[cf], 16, 64);
    rsum[cf] += __shfl_xor(rsum[cf], 32, 64);
    rsum[cf] = 1.0f / rsum[cf];
  }
  f32x4 oacc[4][2] = {};
#pragma unroll
  for (int kb = 0; kb < 4; ++kb) {
    half8 pb[2];
#pragma unroll
    for (int cf = 0; cf < 2; ++cf) {
      half8 tt;
#pragma unroll
      for (int hb = 0; hb < 8; ++hb)
        tt[hb] = (h16)sacc[2 * kb + (hb >> 2)][cf][hb & 3];
      pb[cf] = tt;
    }
#pragma unroll
    for (int dR = 0; dR < 4; ++dR) {
      int dd = dR * 16 + l15;
      half8 va = *(const half8*)(Vb + dd * 128 + kb * 32 +
                                 ((g4 + (dd >> 1)) & 3) * 8);
      oacc[dR][0] = MFMA16(va, pb[0], oacc[dR][0]);
      oacc[dR][1] = MFMA16(va, pb[1], oacc[dR][1]);
    }
  }
#pragma unroll
  for (int dR = 0; dR < 4; ++dR)
#pragma unroll
    for (int cf = 0; cf < 2; ++cf) {
      int tok127 = w * 32 + cf * 16 + l15;
      size_t token = (size_t)blk * 128 + tok127;
      half4 v4;
#pragma unroll
      for (int r = 0; r < 4; ++r) v4[r] = (h16)(oacc[dR][cf][r] * rsum[cf]);
      *(half4*)&ao[token * 1024 + (2 * head + (dR >> 1)) * 32 +
                   ((g4 + (tok127 >> 1)) & 3) * 8 + (dR & 1) * 4] = v4;
    }
}

// ----------------- kernel 5: out = ao * Wo^T + bo (fp32) -------------------
__global__ __launch_bounds__(512, 2) void k_outproj(
    const h16* __restrict__ ao, const h16* __restrict__ Wto,
    const float* __restrict__ bo, float* __restrict__ out) {
  int bid = blockIdx.x;                       // 256 = 8 XCD x 32
  int wg = (bid & 7) * 32 + (bid >> 3);
  int mt = wg >> 2, nt = wg & 3;
  int tid = threadIdx.x;
  f32x4 acc[8][4] = {};
  gemm256(ao + (size_t)mt * 256 * 1024, Wto + (size_t)nt * 256 * 1024, tid, acc);

  const int w = tid >> 6, lane = tid & 63, l15 = lane & 15, g4 = lane >> 4;
  const int wr = w >> 2, wc = w & 3;
#pragma unroll
  for (int fi = 0; fi < 8; ++fi)
#pragma unroll
    for (int fj = 0; fj < 4; ++fj) {
      int col = nt * 256 + wc * 64 + fj * 16 + l15;
      float bb = bo[col];
      size_t rowb = (size_t)mt * 256 + wr * 128 + fi * 16 + 4 * g4;
#pragma unroll
      for (int rr = 0; rr < 4; ++rr)
        out[(rowb + rr) * 1024 + col] = acc[fi][fj][rr] + bb;
    }
}

// ---------------------------------------------------------------------------
extern "C" void kernel_launch(void* const* d_in, const int* in_sizes, int n_in,
                              void* d_out, int out_size, void* d_ws, size_t ws_size,
                              hipStream_t stream) {
  const float* x  = (const float*)d_in[0];
  const float* Wq = (const float*)d_in[1];
  const float* bq = (const float*)d_in[2];
  const float* Wk = (const float*)d_in[3];
  const float* bk = (const float*)d_in[4];
  const float* Wv = (const float*)d_in[5];
  const float* bv = (const float*)d_in[6];
  const float* Wo = (const float*)d_in[7];
  const float* bo = (const float*)d_in[8];
  float* out = (float*)d_out;

  char* ws = (char*)d_ws;                  // needs >= 136 MB
  h16* xh = (h16*)ws;                      // 32 MB (reused as ao after QKV GEMM)
  h16* wt = (h16*)(ws + (32u << 20));      // 8 MB: q,k,v,o consecutive
  h16* Qp = (h16*)(ws + (40u << 20));      // 32 MB
  h16* Kp = (h16*)(ws + (72u << 20));      // 32 MB
  h16* Vp = (h16*)(ws + (104u << 20));     // 32 MB
  h16* ao = xh;                            // alias: xh dead after k_gemm_qkv

  k_cvt_x<<<2048, 256, 0, stream>>>(x, xh);
  k_cvt_w<<<2048, 256, 0, stream>>>(Wq, Wk, Wv, Wo, wt);
  k_gemm_qkv<<<768, 512, 0, stream>>>(xh, wt, bq, bk, bv, Qp, Kp, Vp);
  k_attn<<<2048, 256, 0, stream>>>(Qp, Kp, Vp, ao);
  k_outproj<<<256, 512, 0, stream>>>(ao, wt + 3u * 1024 * 1024, bo, out);
}

// Round 7
// 348.552 us; speedup vs baseline: 1.0993x; 1.0069x over previous
//
#include <hip/hip_runtime.h>

// ---------------------------------------------------------------------------
// BlockSparseAttention — fp16-MFMA pipeline, 256^2 single-barrier 4-phase (v5)
//  1) k_cvt_x : x fp32 -> xh fp16, swizzled row layout          (unchanged)
//  2) k_cvt_w : W* fp32 -> Wt[n][k] fp16 swizzled, 4 mats       (unchanged)
//  3) k_gemm_qkv: [16384x1024]x[1024x3072], 256^2 tile, BK=64, 8 waves.
//     Core: 4 phases/K-tile, ONE barrier per phase, balanced reads
//     (8,4,8,4 b128; b-regs reused), counted vmcnt(4) at P1/P3 only.
//  4) k_attn : per (blk,head), 4 waves, zero LDS / zero barriers (unchanged)
//  5) k_outproj: same core, fp32 + bias out.
// Swizzle (all fp16 operand matrices): within each row's 64B k-tile (32 k),
// k-group g stored at 16B-slot (g + (row>>1)) & 3; frag ds_read slot
// (g4+(l15>>1))&3 -> conflict-free (r3-verified: SQ_LDS_BANK_CONFLICT = 0).
// Single-barrier safety: stages write tile(t+1) buffers; their previous
// readers (tile t-1) are lgkm-drained >= 1 barrier earlier on every wave.
// Workspace (needs >= 136 MB): [0,32M) xh then ao | [32M,40M) Wt q,k,v,o |
// [40,72) Qp | [72,104) Kp | [104,136) Vp.
// ---------------------------------------------------------------------------

typedef _Float16 h16;
typedef _Float16 half8 __attribute__((ext_vector_type(8)));
typedef _Float16 half4 __attribute__((ext_vector_type(4)));
typedef float    f32x4 __attribute__((ext_vector_type(4)));
typedef float    fvec4 __attribute__((ext_vector_type(4)));

__device__ __forceinline__ void gload16(const void* g, void* l) {
  __builtin_amdgcn_global_load_lds(
      (const __attribute__((address_space(1))) unsigned int*)g,
      (__attribute__((address_space(3))) unsigned int*)l, 16, 0, 0);
}
#define MFMA16(a, b, c) __builtin_amdgcn_mfma_f32_16x16x32_f16(a, b, c, 0, 0, 0)

// ---------------- kernel 1: x fp32 -> fp16, swizzled -----------------------
__global__ __launch_bounds__(256) void k_cvt_x(const float* __restrict__ x,
                                               h16* __restrict__ xh) {
  size_t t = (size_t)blockIdx.x * 256 + threadIdx.x;
  int token = (int)(t >> 5);
  const fvec4* src = (const fvec4*)(x + t * 32);
  fvec4 f[8];
#pragma unroll
  for (int m = 0; m < 8; ++m) f[m] = src[m];
  h16* dst = xh + t * 32;
#pragma unroll
  for (int t4 = 0; t4 < 4; ++t4) {
    int g = (t4 - (token >> 1)) & 3;
    half8 o;
#pragma unroll
    for (int j = 0; j < 8; ++j) o[j] = (h16)f[g + 4 * (j >> 2)][j & 3];
    *(half8*)(dst + t4 * 8) = o;
  }
}

// ------- kernel 2: W[k][n] fp32 -> Wt[n][k] fp16 swizzled, 4 mats ----------
__global__ __launch_bounds__(256) void k_cvt_w(
    const float* __restrict__ W0, const float* __restrict__ W1,
    const float* __restrict__ W2, const float* __restrict__ W3,
    h16* __restrict__ Wt_all) {
  __shared__ float T[64][33];
  int bid = blockIdx.x;
  int mat = bid >> 9, b2 = bid & 511;
  const float* W = (mat == 0) ? W0 : (mat == 1) ? W1 : (mat == 2) ? W2 : W3;
  h16* Wt = Wt_all + (size_t)mat * 1024 * 1024;
  int n0 = (b2 & 31) * 32;
  int k0 = (b2 >> 5) * 64;
  int tid = threadIdx.x;
#pragma unroll
  for (int it = 0; it < 2; ++it) {
    int s = it * 256 + tid;
    int r = s >> 3, c4 = s & 7;
    fvec4 v = *(const fvec4*)(W + (size_t)(k0 + r) * 1024 + n0 + c4 * 4);
#pragma unroll
    for (int j = 0; j < 4; ++j) T[r][c4 * 4 + j] = v[j];
  }
  __syncthreads();
  int n = tid >> 3, j = tid & 7;
  int kb = j >> 2, g = j & 3;
  half8 o;
#pragma unroll
  for (int h = 0; h < 2; ++h)
#pragma unroll
    for (int b = 0; b < 4; ++b)
      o[h * 4 + b] = (h16)T[kb * 32 + 4 * g + 16 * h + b][n];
  int nn = n0 + n;
  int slot = (g + (nn >> 1)) & 3;
  *(half8*)(Wt + (size_t)nn * 1024 + ((k0 >> 5) + kb) * 32 + slot * 8) = o;
}

// --------- 256^2 / BK=64 single-barrier 4-phase pipelined GEMM core --------
// Phases per K-tile t (kk halves 0/1, fi halves lo/hi), 16 MFMA each:
//   P0: read a[0..3]k0 + b0[0..3] (8) ; stage A0(t+1)            ; MFMA lo,k0
//   P1: read a[4..7]k0          (4)  ; stage B0(t+1) ; vmcnt(4)  ; MFMA hi,k0
//   P2: read a[0..3]k1 + b1[0..3](8) ; stage A1(t+1)             ; MFMA lo,k1
//   P3: read a[4..7]k1          (4)  ; stage B1(t+1) ; vmcnt(4)  ; MFMA hi,k1
// vmcnt(4) @P1 gates P2's A1(t),B1(t); @P3 gates P0's A0,B0(t+1). Never 0
// in steady state. One barrier per phase (write targets are t+1 buffers,
// prior readers drained >=1 barrier earlier).
__device__ __forceinline__ void gemm256(const h16* __restrict__ Ag,
                                        const h16* __restrict__ Bg,
                                        int tid, f32x4 (&acc)[8][4]) {
  __shared__ h16 LA[4][8192];  // [buf*2+kk][256 rows * 32 halves]
  __shared__ h16 LB[4][8192];
  const int w = tid >> 6, lane = tid & 63, l15 = lane & 15, g4 = lane >> 4;
  const int wr = w >> 2, wc = w & 3;
  const int slotr = ((g4 + (l15 >> 1)) & 3) * 8;
  const int arow0 = (wr * 128 + l15) * 32 + slotr;  // + fi*512
  const int brow0 = (wc * 64 + l15) * 32 + slotr;   // + fj*512

  auto stage = [&](const h16* g0, h16* ldsu) {      // one 16KB unit, 2 gloads
#pragma unroll
    for (int j = 0; j < 2; ++j) {
      int idx = j * 512 + tid;
      gload16(g0 + (size_t)(idx >> 2) * 1024 + (idx & 3) * 8,
              ldsu + (j * 512 + w * 64) * 8);
    }
  };

  // prologue: tile 0 in consumption order A0,B0,A1,B1
  stage(Ag + 0, LA[0]);
  stage(Bg + 0, LB[0]);
  stage(Ag + 32, LA[1]);
  stage(Bg + 32, LB[1]);
  asm volatile("s_waitcnt vmcnt(4)" ::: "memory");  // A0,B0 landed
  __builtin_amdgcn_s_barrier();

  half8 a[4], b[4];
  for (int t = 0; t < 16; ++t) {
    const int cb = (t & 1) * 2, nb = cb ^ 2;
    const bool pre = (t + 1) < 16;
    const h16* An = Ag + (size_t)(2 * (t + 1)) * 32;
    const h16* Bn = Bg + (size_t)(2 * (t + 1)) * 32;
    // ---- P0: acc[0..3] @ kk0 ----
#pragma unroll
    for (int fi = 0; fi < 4; ++fi) a[fi] = *(const half8*)&LA[cb][arow0 + fi * 512];
#pragma unroll
    for (int fj = 0; fj < 4; ++fj) b[fj] = *(const half8*)&LB[cb][brow0 + fj * 512];
    if (pre) stage(An, LA[nb]);
    __builtin_amdgcn_s_barrier();
    asm volatile("s_waitcnt lgkmcnt(0)" ::: "memory");
    __builtin_amdgcn_sched_barrier(0);
    __builtin_amdgcn_s_setprio(1);
#pragma unroll
    for (int fi = 0; fi < 4; ++fi)
#pragma unroll
      for (int fj = 0; fj < 4; ++fj) acc[fi][fj] = MFMA16(a[fi], b[fj], acc[fi][fj]);
    __builtin_amdgcn_s_setprio(0);
    // ---- P1: acc[4..7] @ kk0 ----
#pragma unroll
    for (int fi = 0; fi < 4; ++fi)
      a[fi] = *(const half8*)&LA[cb][arow0 + (4 + fi) * 512];
    if (pre) stage(Bn, LB[nb]);
    if (pre) asm volatile("s_waitcnt vmcnt(4)" ::: "memory");  // A1,B1(t) landed
    else     asm volatile("s_waitcnt vmcnt(0)" ::: "memory");
    __builtin_amdgcn_s_barrier();
    asm volatile("s_waitcnt lgkmcnt(0)" ::: "memory");
    __builtin_amdgcn_sched_barrier(0);
    __builtin_amdgcn_s_setprio(1);
#pragma unroll
    for (int fi = 0; fi < 4; ++fi)
#pragma unroll
      for (int fj = 0; fj < 4; ++fj)
        acc[4 + fi][fj] = MFMA16(a[fi], b[fj], acc[4 + fi][fj]);
    __builtin_amdgcn_s_setprio(0);
    // ---- P2: acc[0..3] @ kk1 ----
#pragma unroll
    for (int fi = 0; fi < 4; ++fi)
      a[fi] = *(const half8*)&LA[cb + 1][arow0 + fi * 512];
#pragma unroll
    for (int fj = 0; fj < 4; ++fj)
      b[fj] = *(const half8*)&LB[cb + 1][brow0 + fj * 512];
    if (pre) stage(An + 32, LA[nb + 1]);
    __builtin_amdgcn_s_barrier();
    asm volatile("s_waitcnt lgkmcnt(0)" ::: "memory");
    __builtin_amdgcn_sched_barrier(0);
    __builtin_amdgcn_s_setprio(1);
#pragma unroll
    for (int fi = 0; fi < 4; ++fi)
#pragma unroll
      for (int fj = 0; fj < 4; ++fj) acc[fi][fj] = MFMA16(a[fi], b[fj], acc[fi][fj]);
    __builtin_amdgcn_s_setprio(0);
    // ---- P3: acc[4..7] @ kk1 ----
#pragma unroll
    for (int fi = 0; fi < 4; ++fi)
      a[fi] = *(const half8*)&LA[cb + 1][arow0 + (4 + fi) * 512];
    if (pre) stage(Bn + 32, LB[nb + 1]);
    if (pre) asm volatile("s_waitcnt vmcnt(4)" ::: "memory");  // A0,B0(t+1) landed
    __builtin_amdgcn_s_barrier();
    asm volatile("s_waitcnt lgkmcnt(0)" ::: "memory");
    __builtin_amdgcn_sched_barrier(0);
    __builtin_amdgcn_s_setprio(1);
#pragma unroll
    for (int fi = 0; fi < 4; ++fi)
#pragma unroll
      for (int fj = 0; fj < 4; ++fj)
        acc[4 + fi][fj] = MFMA16(a[fi], b[fj], acc[4 + fi][fj]);
    __builtin_amdgcn_s_setprio(0);
  }
}

// --------- kernel 3: QKV GEMM 16384x3072, epilogue packs Q/K/V^T -----------
__global__ __launch_bounds__(512, 2) void k_gemm_qkv(
    const h16* __restrict__ xh, const h16* __restrict__ wt,
    const float* __restrict__ bq, const float* __restrict__ bk,
    const float* __restrict__ bv, h16* __restrict__ Qp,
    h16* __restrict__ Kp, h16* __restrict__ Vp) {
  int bid = blockIdx.x;                       // 768 = 8 XCD x 96
  int wg = (bid & 7) * 96 + (bid >> 3);
  int mt = wg / 12, nt = wg - mt * 12;
  int tid = threadIdx.x;
  f32x4 acc[8][4] = {};
  gemm256(xh + (size_t)mt * 256 * 1024, wt + (size_t)nt * 256 * 1024, tid, acc);

  const int w = tid >> 6, lane = tid & 63, l15 = lane & 15, g4 = lane >> 4;
  const int wr = w >> 2, wc = w & 3;
  int mat = nt >> 2;                          // 0=Q 1=K 2=V
  int head = (nt & 3) * 4 + wc;               // wave-uniform
  int blk = mt * 2 + wr;
  size_t bh8k = (size_t)(blk * 16 + head) * 8192;
  const float sc = 0.125f * 1.44269504088896f;  // 1/sqrt(dk)*log2(e)
#pragma unroll
  for (int fi = 0; fi < 8; ++fi)
#pragma unroll
    for (int fj = 0; fj < 4; ++fj) {
      int d = fj * 16 + l15;
      int tok0 = fi * 16 + 4 * g4;
      if (mat == 0) {
        float bias = bq[head * 64 + d];
        int inner = ((d >> 4) & 1) * 4 + (d & 3), gq = (d & 15) >> 2, dk5 = d >> 5;
#pragma unroll
        for (int rr = 0; rr < 4; ++rr) {
          int tok = tok0 + rr;
          Qp[bh8k + tok * 64 + dk5 * 32 + ((gq + (tok >> 1)) & 3) * 8 + inner] =
              (h16)((acc[fi][fj][rr] + bias) * sc);
        }
      } else if (mat == 1) {
        float bias = bk[head * 64 + d];
        int inner = ((d >> 4) & 1) * 4 + (d & 3), gq = (d & 15) >> 2, dk5 = d >> 5;
#pragma unroll
        for (int rr = 0; rr < 4; ++rr) {
          int tok = tok0 + rr;
          Kp[bh8k + tok * 64 + dk5 * 32 + ((gq + (tok >> 1)) & 3) * 8 + inner] =
              (h16)(acc[fi][fj][rr] + bias);
        }
      } else {
        float bias = bv[head * 64 + d];
        half4 v4;
#pragma unroll
        for (int rr = 0; rr < 4; ++rr) v4[rr] = (h16)(acc[fi][fj][rr] + bias);
        *(half4*)&Vp[bh8k + d * 128 + (fi >> 1) * 32 +
                     ((g4 + (d >> 1)) & 3) * 8 + (fi & 1) * 4] = v4;
      }
    }
}

// --------- kernel 4: block attention, zero LDS / zero barriers -------------
__global__ __launch_bounds__(256) void k_attn(
    const h16* __restrict__ Qp, const h16* __restrict__ Kp,
    const h16* __restrict__ Vp, h16* __restrict__ ao) {
  int bh = blockIdx.x;                       // 2048 = 128 blk x 16 heads
  int blk = bh >> 4, head = bh & 15;
  int tid = threadIdx.x, w = tid >> 6, lane = tid & 63;
  int l15 = lane & 15, g4 = lane >> 4;
  const h16* Qb = Qp + (size_t)bh * 8192;
  const h16* Kb = Kp + (size_t)bh * 8192;
  const h16* Vb = Vp + (size_t)bh * 8192;

  half8 qb[2][2];
#pragma unroll
  for (int cf = 0; cf < 2; ++cf)
#pragma unroll
    for (int k2 = 0; k2 < 2; ++k2) {
      int q = w * 32 + cf * 16 + l15;
      qb[cf][k2] = *(const half8*)(Qb + q * 64 + k2 * 32 + ((g4 + (q >> 1)) & 3) * 8);
    }
  f32x4 sacc[8][2] = {};
#pragma unroll
  for (int k2 = 0; k2 < 2; ++k2)
#pragma unroll
    for (int Rf = 0; Rf < 8; ++Rf) {
      int kv = Rf * 16 + l15;
      half8 ka = *(const half8*)(Kb + kv * 64 + k2 * 32 + ((g4 + (kv >> 1)) & 3) * 8);
      sacc[Rf][0] = MFMA16(ka, qb[0][k2], sacc[Rf][0]);
      sacc[Rf][1] = MFMA16(ka, qb[1][k2], sacc[Rf][1]);
    }
  float rmax[2] = {-1e30f, -1e30f};
#pragma unroll
  for (int Rf = 0; Rf < 8; ++Rf)
#pragma unroll
    for (int cf = 0; cf < 2; ++cf)
#pragma unroll
      for (int r = 0; r < 4; ++r) rmax[cf] = fmaxf(rmax[cf], sacc[Rf][cf][r]);
#pragma unroll
  for (int cf = 0; cf < 2; ++cf) {
    rmax[cf] = fmaxf(rmax[cf], __shfl_xor(rmax[cf], 16, 64));
    rmax[cf] = fmaxf(rmax[cf], __shfl_xor(rmax[cf], 32, 64));
  }
  float rsum[2] = {0.f, 0.f};
#pragma unroll
  for (int Rf = 0; Rf < 8; ++Rf)
#pragma unroll
    for (int cf = 0; cf < 2; ++cf)
#pragma unroll
      for (int r = 0; r < 4; ++r) {
        float p = exp2f(sacc[Rf][cf][r] - rmax[cf]);
        sacc[Rf][cf][r] = p;
        rsum[cf] += p;
      }
#pragma unroll
  for (int cf = 0; cf < 2; ++cf) {
    rsum[cf] += __shfl_xor(rsum[cf], 16, 64);
    rsum[cf] += __shfl_xor(rsum[cf], 32, 64);
    rsum[cf] = 1.0f / rsum[cf];
  }
  f32x4 oacc[4][2] = {};
#pragma unroll
  for (int kb = 0; kb < 4; ++kb) {
    half8 pb[2];
#pragma unroll
    for (int cf = 0; cf < 2; ++cf) {
      half8 tt;
#pragma unroll
      for (int hb = 0; hb < 8; ++hb)
        tt[hb] = (h16)sacc[2 * kb + (hb >> 2)][cf][hb & 3];
      pb[cf] = tt;
    }
#pragma unroll
    for (int dR = 0; dR < 4; ++dR) {
      int dd = dR * 16 + l15;
      half8 va = *(const half8*)(Vb + dd * 128 + kb * 32 +
                                 ((g4 + (dd >> 1)) & 3) * 8);
      oacc[dR][0] = MFMA16(va, pb[0], oacc[dR][0]);
      oacc[dR][1] = MFMA16(va, pb[1], oacc[dR][1]);
    }
  }
#pragma unroll
  for (int dR = 0; dR < 4; ++dR)
#pragma unroll
    for (int cf = 0; cf < 2; ++cf) {
      int tok127 = w * 32 + cf * 16 + l15;
      size_t token = (size_t)blk * 128 + tok127;
      half4 v4;
#pragma unroll
      for (int r = 0; r < 4; ++r) v4[r] = (h16)(oacc[dR][cf][r] * rsum[cf]);
      *(half4*)&ao[token * 1024 + (2 * head + (dR >> 1)) * 32 +
                   ((g4 + (tok127 >> 1)) & 3) * 8 + (dR & 1) * 4] = v4;
    }
}

// ----------------- kernel 5: out = ao * Wo^T + bo (fp32) -------------------
__global__ __launch_bounds__(512, 2) void k_outproj(
    const h16* __restrict__ ao, const h16* __restrict__ Wto,
    const float* __restrict__ bo, float* __restrict__ out) {
  int bid = blockIdx.x;                       // 256 = 8 XCD x 32
  int wg = (bid & 7) * 32 + (bid >> 3);
  int mt = wg >> 2, nt = wg & 3;
  int tid = threadIdx.x;
  f32x4 acc[8][4] = {};
  gemm256(ao + (size_t)mt * 256 * 1024, Wto + (size_t)nt * 256 * 1024, tid, acc);

  const int w = tid >> 6, lane = tid & 63, l15 = lane & 15, g4 = lane >> 4;
  const int wr = w >> 2, wc = w & 3;
#pragma unroll
  for (int fi = 0; fi < 8; ++fi)
#pragma unroll
    for (int fj = 0; fj < 4; ++fj) {
      int col = nt * 256 + wc * 64 + fj * 16 + l15;
      float bb = bo[col];
      size_t rowb = (size_t)mt * 256 + wr * 128 + fi * 16 + 4 * g4;
#pragma unroll
      for (int rr = 0; rr < 4; ++rr)
        out[(rowb + rr) * 1024 + col] = acc[fi][fj][rr] + bb;
    }
}

// ---------------------------------------------------------------------------
extern "C" void kernel_launch(void* const* d_in, const int* in_sizes, int n_in,
                              void* d_out, int out_size, void* d_ws, size_t ws_size,
                              hipStream_t stream) {
  const float* x  = (const float*)d_in[0];
  const float* Wq = (const float*)d_in[1];
  const float* bq = (const float*)d_in[2];
  const float* Wk = (const float*)d_in[3];
  const float* bk = (const float*)d_in[4];
  const float* Wv = (const float*)d_in[5];
  const float* bv = (const float*)d_in[6];
  const float* Wo = (const float*)d_in[7];
  const float* bo = (const float*)d_in[8];
  float* out = (float*)d_out;

  char* ws = (char*)d_ws;                  // needs >= 136 MB
  h16* xh = (h16*)ws;                      // 32 MB (reused as ao after QKV GEMM)
  h16* wt = (h16*)(ws + (32u << 20));      // 8 MB: q,k,v,o consecutive
  h16* Qp = (h16*)(ws + (40u << 20));      // 32 MB
  h16* Kp = (h16*)(ws + (72u << 20));      // 32 MB
  h16* Vp = (h16*)(ws + (104u << 20));     // 32 MB
  h16* ao = xh;                            // alias: xh dead after k_gemm_qkv

  k_cvt_x<<<2048, 256, 0, stream>>>(x, xh);
  k_cvt_w<<<2048, 256, 0, stream>>>(Wq, Wk, Wv, Wo, wt);
  k_gemm_qkv<<<768, 512, 0, stream>>>(xh, wt, bq, bk, bv, Qp, Kp, Vp);
  k_attn<<<2048, 256, 0, stream>>>(Qp, Kp, Vp, ao);
  k_outproj<<<256, 512, 0, stream>>>(ao, wt + 3u * 1024 * 1024, bo, out);
}